// Round 10
// baseline (270.105 us; speedup 1.0000x reference)
//
#include <hip/hip_runtime.h>
#include <cstdint>
#include <cstddef>

// Problem constants (VectorQuantizer: L=32768, D=64, N_E=16384, beta=0.25)
#define L_TOK 32768
#define D_DIM 64
#define NE    16384
#define GCHUNKS 8              // N split across grid (8 -> 8192 waves total)
#define NPB   (NE / GCHUNKS)   // 2048 n per block
#define BN    256              // n per LDS stage chunk
#define NCH   (NPB / BN)       // 8 chunks per block
#define WROWS 32               // rows per wave (2 MFMA row-groups)
#define BROWS 256              // rows per block (8 waves x 32)
#define RBLOCKS  (L_TOK / 32)  // 1024 refine blocks

#define ASCALE  -4194304.0f    // -2^22: A-fragment pre-scale (exact pow2)
#define ESCALE   2097152.0f    // 2^21 = 0.5*2^22 for esq
#define KBIAS_F  32768.0f      // 2^15 bias, folded into esqs at prep

typedef unsigned short ushort_t;
typedef __attribute__((ext_vector_type(8))) short bf16x8;
typedef __attribute__((ext_vector_type(4))) float f32x4;

// ---- ws layout (bytes) ----
#define WS_EHI   0u                                  // 2 MB   e bf16(RNE) permuted
#define WS_ESQ32 (2u<<20)                            // 64 KB  esq np-exact fp32
#define WS_ESQS  ((2u<<20) + (64u<<10))              // 64 KB  esq*2^21 + 2^15
#define WS_ESQ64 ((2u<<20) + (128u<<10))             // 128 KB esq fp64 (loss)
#define WS_CAND  ((2u<<20) + (256u<<10))             // 4 MB   cand[8][L][4] int
#define WS_PART  ((6u<<20) + (256u<<10))             // 8 KB   loss partials (1024 dbl)

__device__ __forceinline__ ushort_t bf16_rne(float v) {
  unsigned u = __float_as_uint(v);
  return (ushort_t)((u + 0x7fffu + ((u >> 16) & 1u)) >> 16);
}

// v_med3_u32: median(a,b,c). With b<=c this equals min(max(a,b),c) — the
// top-k insertion step. The compiler can't prove the invariant, so ask for
// the instruction directly.
__device__ __forceinline__ unsigned umed3(unsigned a, unsigned b, unsigned c) {
  unsigned d;
  asm("v_med3_u32 %0, %1, %2, %3" : "=v"(d) : "v"(a), "v"(b), "v"(c));
  return d;
}

// numpy pairwise_sum emulation for n=64 contiguous fp32 (scalar 8-acc path).
__device__ __forceinline__ float np_sum64(float a) {
  int j = threadIdx.x & 7;
  float r = __shfl(a, j);
  #pragma unroll
  for (int m = 1; m < 8; ++m) r += __shfl(a, j + 8 * m);
  float s0 = __shfl(r, 0), s1 = __shfl(r, 1), s2 = __shfl(r, 2), s3 = __shfl(r, 3);
  float s4 = __shfl(r, 4), s5 = __shfl(r, 5), s6 = __shfl(r, 6), s7 = __shfl(r, 7);
  return ((s0 + s1) + (s2 + s3)) + ((s4 + s5) + (s6 + s7));
}

// Fragment-permuted index (in ushorts) for element (n, k) — LDS staging order
// equals MFMA B-fragment consumption order (conflict-free ds_read_b128).
__device__ __forceinline__ int perm_off(int n, int k) {
  int tile = n >> 4, c = n & 15, s = k >> 5, q = (k >> 3) & 3, j = k & 7;
  return tile * 1024 + s * 512 + (q * 16 + c) * 8 + j;
}

// ---------------- kernel 1: prep embedding -----------------------------------
__global__ __launch_bounds__(256) void vq_prep_e(const float* __restrict__ e,
                                                 ushort_t* __restrict__ ehi,
                                                 float* __restrict__ esq32,
                                                 float* __restrict__ esqs,
                                                 double* __restrict__ esq64) {
  int wave = threadIdx.x >> 6, lane = threadIdx.x & 63;
  int row = blockIdx.x * 4 + wave;            // one wave per embedding row
  float v = e[(size_t)row * D_DIM + lane];
  ehi[perm_off(row, lane)] = bf16_rne(v);
  float esq = np_sum64(v * v);                // numpy-bit-exact sum(e*e, axis=1)
  double p = (double)v * (double)v;
  #pragma unroll
  for (int o = 32; o; o >>= 1) p += __shfl_xor(p, o);
  if (lane == 0) {
    esq32[row] = esq;                         // exact rescore
    esqs[row]  = esq * ESCALE + KBIAS_F;      // sieve MFMA C operand
    esq64[row] = p;                           // loss
  }
}

// ---------------- kernel 2: fused distance + per-row top-k sieve -------------
// grid = dim3(GCHUNKS, L/BROWS) = 1024 blocks, block = 512 (8 waves x 32 rows)
// Staging is software-pipelined: chunk cb+1 is prefetched into registers while
// chunk cb computes, so the vmcnt drain before the LDS write finds data
// already arrived (removes the per-chunk global-latency stall).
// A is pre-scaled by -2^22, esq*2^21+2^15 rides as the MFMA C operand, so
// acc == 2^22*d + 2^15 (positive by Cauchy-Schwarz: |dot|*2^22 < 24.7k < 2^15).
// Packed key: (trunc(acc) << 12) | (tile*16+c).  Per-lane top-2 -> per-row
// top-4 per 2048-chunk (np-winner missing needs >=4 sieve-better entries in
// its chunk within the ~8e-6 window — quartic-rare); refine resolves exactly.
__global__ __launch_bounds__(512, 8) void vq_argmin(const float* __restrict__ z,
                                                    const ushort_t* __restrict__ ehi,
                                                    const float* __restrict__ esqs,
                                                    int* __restrict__ cand) {
  __shared__ __align__(16) unsigned char smem[33792]; // staging 33KB / merge 32KB
  ushort_t* s_ehi = (ushort_t*)smem;
  float*    s_esq = (float*)(smem + 32768);

  const int tid = threadIdx.x;
  const int wave = tid >> 6, lane = tid & 63;
  const int q = lane >> 4, c = lane & 15;
  const int row0 = blockIdx.y * BROWS + wave * WROWS;
  const int nbase = blockIdx.x * NPB;

  // A fragments: two row-groups of 16, bf16(RNE) of -2^22*z in-register.
  // A layout: lane holds A[m=lane&15][k = q*8 + j (+32 for k-step 1)]
  bf16x8 zA[2][2];
  #pragma unroll
  for (int g = 0; g < 2; ++g) {
    const float* zr = z + (size_t)(row0 + g * 16 + c) * D_DIM;
    float4 a0 = *(const float4*)(zr + q * 8);
    float4 a1 = *(const float4*)(zr + q * 8 + 4);
    float4 a2 = *(const float4*)(zr + 32 + q * 8);
    float4 a3 = *(const float4*)(zr + 32 + q * 8 + 4);
    zA[g][0][0] = (short)bf16_rne(a0.x * ASCALE); zA[g][0][1] = (short)bf16_rne(a0.y * ASCALE);
    zA[g][0][2] = (short)bf16_rne(a0.z * ASCALE); zA[g][0][3] = (short)bf16_rne(a0.w * ASCALE);
    zA[g][0][4] = (short)bf16_rne(a1.x * ASCALE); zA[g][0][5] = (short)bf16_rne(a1.y * ASCALE);
    zA[g][0][6] = (short)bf16_rne(a1.z * ASCALE); zA[g][0][7] = (short)bf16_rne(a1.w * ASCALE);
    zA[g][1][0] = (short)bf16_rne(a2.x * ASCALE); zA[g][1][1] = (short)bf16_rne(a2.y * ASCALE);
    zA[g][1][2] = (short)bf16_rne(a2.z * ASCALE); zA[g][1][3] = (short)bf16_rne(a2.w * ASCALE);
    zA[g][1][4] = (short)bf16_rne(a3.x * ASCALE); zA[g][1][5] = (short)bf16_rne(a3.y * ASCALE);
    zA[g][1][6] = (short)bf16_rne(a3.z * ASCALE); zA[g][1][7] = (short)bf16_rne(a3.w * ASCALE);
  }

  // per-(rowgroup g, acc row r) top-2 packed-key tracking (16 VGPRs),
  // invariant K0 <= K1 (init equal, preserved by med3 insertion)
  unsigned K0[2][4], K1[2][4];
  #pragma unroll
  for (int g = 0; g < 2; ++g)
    #pragma unroll
    for (int r = 0; r < 4; ++r) { K0[g][r] = 0xFFFFFFFFu; K1[g][r] = 0xFFFFFFFFu; }

  // staging prefetch registers (chunk pipeline)
  uint4 pr0, pr1, pr2, pr3; float presq;
  {
    const uint4* gh = ((const uint4*)ehi) + (size_t)nbase * 8;
    pr0 = gh[tid]; pr1 = gh[tid + 512]; pr2 = gh[tid + 1024]; pr3 = gh[tid + 1536];
    presq = (tid < BN) ? esqs[nbase + tid] : 0.f;
  }

  for (int cb = 0; cb < NCH; ++cb) {
    __syncthreads();   // previous chunk's LDS reads done
    {
      uint4* sb = (uint4*)s_ehi;                                // 2048 uint4
      sb[tid] = pr0; sb[tid + 512] = pr1; sb[tid + 1024] = pr2; sb[tid + 1536] = pr3;
      if (tid < BN) s_esq[tid] = presq;
    }
    __syncthreads();
    if (cb + 1 < NCH) {      // issue next chunk's loads; latency hides under compute
      int nnext = nbase + (cb + 1) * BN;
      const uint4* gh = ((const uint4*)ehi) + (size_t)nnext * 8;
      pr0 = gh[tid]; pr1 = gh[tid + 512]; pr2 = gh[tid + 1024]; pr3 = gh[tid + 1536];
      presq = (tid < BN) ? esqs[nnext + tid] : 0.f;
    }

    #pragma unroll 4
    for (int t = 0; t < BN / 16; ++t) {
      const bf16x8 bh0 = *(const bf16x8*)(s_ehi + t * 1024 + lane * 8);
      const bf16x8 bh1 = *(const bf16x8*)(s_ehi + t * 1024 + 512 + lane * 8);
      float esqv = s_esq[t * 16 + c];
      f32x4 cvec = {esqv, esqv, esqv, esqv};       // key bias rides in as C
      unsigned tcv = (((unsigned)(cb * 16 + t)) << 4) | (unsigned)c;  // n_local
      f32x4 acc0 = __builtin_amdgcn_mfma_f32_16x16x32_bf16(zA[0][0], bh0, cvec, 0, 0, 0);
      acc0 = __builtin_amdgcn_mfma_f32_16x16x32_bf16(zA[0][1], bh1, acc0, 0, 0, 0);
      f32x4 acc1 = __builtin_amdgcn_mfma_f32_16x16x32_bf16(zA[1][0], bh0, cvec, 0, 0, 0);
      acc1 = __builtin_amdgcn_mfma_f32_16x16x32_bf16(zA[1][1], bh1, acc1, 0, 0, 0);
      #pragma unroll
      for (int r = 0; r < 4; ++r) {
        unsigned pk = (((unsigned)acc0[r]) << 12) | tcv;   // cvt + lshl_or
        K1[0][r] = umed3(pk, K0[0][r], K1[0][r]);
        K0[0][r] = min(pk, K0[0][r]);
      }
      #pragma unroll
      for (int r = 0; r < 4; ++r) {
        unsigned pk = (((unsigned)acc1[r]) << 12) | tcv;
        K1[1][r] = umed3(pk, K0[1][r], K1[1][r]);
        K0[1][r] = min(pk, K0[1][r]);
      }
    }
  }

  // merge 16 lanes' top-2 -> per-row top-4 for this chunk
  __syncthreads();
  unsigned* s_k = (unsigned*)smem;             // [256 rows][16 c][2] = 32 KB
  #pragma unroll
  for (int g = 0; g < 2; ++g)
    #pragma unroll
    for (int r = 0; r < 4; ++r) {
      int rowidx = wave * WROWS + g * 16 + q * 4 + r;  // C layout: row = q*4 + reg
      int base = (rowidx * 16 + c) * 2;
      s_k[base + 0] = K0[g][r]; s_k[base + 1] = K1[g][r];
    }
  __syncthreads();
  if (tid < BROWS) {
    unsigned M0 = 0xFFFFFFFFu, M1 = 0xFFFFFFFFu, M2 = 0xFFFFFFFFu, M3 = 0xFFFFFFFFu;
    const uint4* sv = (const uint4*)(s_k + tid * 32);
    #pragma unroll
    for (int v4 = 0; v4 < 8; ++v4) {
      uint4 kk = sv[v4];
      unsigned vals[4] = {kk.x, kk.y, kk.z, kk.w};
      #pragma unroll
      for (int u = 0; u < 4; ++u) {
        unsigned v = vals[u];
        M3 = umed3(v, M2, M3);
        M2 = umed3(v, M1, M2);
        M1 = umed3(v, M0, M1);
        M0 = min(v, M0);
      }
    }
    int grow = blockIdx.y * BROWS + tid;
    int* cp = cand + ((size_t)blockIdx.x * L_TOK + grow) * 4;
    cp[0] = (int)(nbase + (M0 & 4095u)); cp[1] = (int)(nbase + (M1 & 4095u));
    cp[2] = (int)(nbase + (M2 & 4095u)); cp[3] = (int)(nbase + (M3 & 4095u));
  }
}

// ------- kernel 3: np-fp32-exact rescore of 32 candidates, outputs ----------
// grid = L/32 blocks, block 512 (8 waves); each wave: 4 rows, one row per
// iter with 32 cand-groups x 2 lanes.  All 16 float4 loads issued up front;
// fp64 dot uses 4 independent accumulators (chain 8-deep, not 32).
__global__ __launch_bounds__(512, 4) void vq_refine(const float* __restrict__ z,
                                                    const float* __restrict__ e,
                                                    const float* __restrict__ esq32,
                                                    const double* __restrict__ esq64,
                                                    const int* __restrict__ cand,
                                                    float* __restrict__ out,
                                                    double* __restrict__ partials) {
  const int tid = threadIdx.x;
  const int wave = tid >> 6, lane = tid & 63;
  const int g = lane >> 1, s = lane & 1;      // 32 cand-groups x 2 lanes
  __shared__ double sp[8];
  double wl = 0.0;
  for (int it = 0; it < 4; ++it) {
    int row = blockIdx.x * 32 + wave * 4 + it;
    float zf = z[(size_t)row * D_DIM + lane];
    float zsqv = np_sum64(zf * zf);            // numpy-bit-exact sum(z*z, axis=1)
    double zp64 = (double)zf * (double)zf;
    #pragma unroll
    for (int o = 32; o; o >>= 1) zp64 += __shfl_xor(zp64, o);
    int idx = cand[((size_t)(g >> 2) * L_TOK + row) * 4 + (g & 3)];
    // fp64 dot over 32 elements/lane: issue all loads, 4 indep accumulators
    const float4* ep = (const float4*)(e + (size_t)idx * D_DIM + s * 32);
    const float4* zp = (const float4*)(z + (size_t)row * D_DIM + s * 32);
    float4 ev[8], zv[8];
    #pragma unroll
    for (int j = 0; j < 8; ++j) { ev[j] = ep[j]; zv[j] = zp[j]; }
    double da = 0.0, db = 0.0, dc = 0.0, dd = 0.0;
    #pragma unroll
    for (int j = 0; j < 8; j += 4) {
      da = fma((double)ev[j].x,     (double)zv[j].x,     da);
      da = fma((double)ev[j].y,     (double)zv[j].y,     da);
      da = fma((double)ev[j].z,     (double)zv[j].z,     da);
      da = fma((double)ev[j].w,     (double)zv[j].w,     da);
      db = fma((double)ev[j + 1].x, (double)zv[j + 1].x, db);
      db = fma((double)ev[j + 1].y, (double)zv[j + 1].y, db);
      db = fma((double)ev[j + 1].z, (double)zv[j + 1].z, db);
      db = fma((double)ev[j + 1].w, (double)zv[j + 1].w, db);
      dc = fma((double)ev[j + 2].x, (double)zv[j + 2].x, dc);
      dc = fma((double)ev[j + 2].y, (double)zv[j + 2].y, dc);
      dc = fma((double)ev[j + 2].z, (double)zv[j + 2].z, dc);
      dc = fma((double)ev[j + 2].w, (double)zv[j + 2].w, dc);
      dd = fma((double)ev[j + 3].x, (double)zv[j + 3].x, dd);
      dd = fma((double)ev[j + 3].y, (double)zv[j + 3].y, dd);
      dd = fma((double)ev[j + 3].z, (double)zv[j + 3].z, dd);
      dd = fma((double)ev[j + 3].w, (double)zv[j + 3].w, dd);
    }
    double dot = (da + db) + (dc + dd);
    dot += __shfl_xor(dot, 1);
    // emulate np fp32: d = fl32( fl32(zsq + esq) - fl32(2*dot) )
    float t2 = (float)(2.0 * dot);
    float T1 = zsqv + esq32[idx];
    float d  = T1 - t2;                        // d ~ 64 > 0: bits are monotone
    unsigned long long key = ((unsigned long long)__float_as_uint(d) << 14)
                           | (unsigned)idx;    // tie -> lower idx (np.argmin)
    double dotw = dot;
    #pragma unroll
    for (int o = 2; o <= 32; o <<= 1) {
      unsigned long long ok = __shfl_xor(key, o);
      double od = __shfl_xor(dotw, o);
      bool take = ok < key;
      key  = take ? ok : key;
      dotw = take ? od : dotw;
    }
    int win = (int)(key & 16383u);
    // outputs (element layout; whole wave)
    float be = e[(size_t)win * D_DIM + lane];
    out[(size_t)row * D_DIM + lane] = zf + (be - zf);   // fp32 op-order ST
    if (lane == 0) {
      out[(size_t)L_TOK * D_DIM + 1 + row] = (float)win;
      wl += zp64 + esq64[win] - 2.0 * dotw;             // ||z - e_win||^2 (fp64)
    }
  }
  if (lane == 0) sp[wave] = wl;
  __syncthreads();
  if (tid == 0) {
    double t = 0.0;
    #pragma unroll
    for (int w = 0; w < 8; ++w) t += sp[w];
    partials[blockIdx.x] = t;
  }
}

// ---------------- kernel 4: finalize loss (1024 partials) --------------------
__global__ __launch_bounds__(512) void vq_loss(const double* __restrict__ partials,
                                               float* __restrict__ out) {
  int tid = threadIdx.x;
  double v = partials[tid] + partials[tid + 512];
  #pragma unroll
  for (int o = 32; o; o >>= 1) v += __shfl_xor(v, o);
  __shared__ double sp[8];
  if ((tid & 63) == 0) sp[tid >> 6] = v;
  __syncthreads();
  if (tid == 0) {
    double tot = 0.0;
    #pragma unroll
    for (int w = 0; w < 8; ++w) tot += sp[w];
    // loss = beta*mean + mean = 1.25 * mean((z_q - z)^2)
    out[(size_t)L_TOK * D_DIM] = (float)(1.25 * tot / (double)((size_t)L_TOK * D_DIM));
  }
}

extern "C" void kernel_launch(void* const* d_in, const int* in_sizes, int n_in,
                              void* d_out, int out_size, void* d_ws, size_t ws_size,
                              hipStream_t stream) {
  const float* z = (const float*)d_in[0];       // (32768, 64) fp32
  const float* e = (const float*)d_in[1];       // (16384, 64) fp32
  float* out = (float*)d_out;                   // [z_q_st | loss | indices-as-f32]
  char* ws = (char*)d_ws;                       // needs ~6.3 MB

  ushort_t* ehi   = (ushort_t*)(ws + WS_EHI);
  float*    esq32 = (float*)(ws + WS_ESQ32);
  float*    esqs  = (float*)(ws + WS_ESQS);
  double*   esq64 = (double*)(ws + WS_ESQ64);
  int*      cand  = (int*)(ws + WS_CAND);
  double*   parts = (double*)(ws + WS_PART);

  vq_prep_e<<<NE / 4, 256, 0, stream>>>(e, ehi, esq32, esqs, esq64);
  vq_argmin<<<dim3(GCHUNKS, L_TOK / BROWS), 512, 0, stream>>>(z, ehi, esqs, cand);
  vq_refine<<<RBLOCKS, 512, 0, stream>>>(z, e, esq32, esq64, cand, out, parts);
  vq_loss<<<1, 512, 0, stream>>>(parts, out);
}

// Round 11
// 242.768 us; speedup vs baseline: 1.1126x; 1.1126x over previous
//
#include <hip/hip_runtime.h>
#include <cstdint>
#include <cstddef>

// Problem constants (VectorQuantizer: L=32768, D=64, N_E=16384, beta=0.25)
#define L_TOK 32768
#define D_DIM 64
#define NE    16384
#define GCHUNKS 8              // N split across grid (8 -> 8192 waves total)
#define NPB   (NE / GCHUNKS)   // 2048 n per block
#define BN    128              // n per LDS stage chunk (double-buffered)
#define NCH   (NPB / BN)       // 16 chunks per block
#define WROWS 32               // rows per wave (2 MFMA row-groups)
#define BROWS 256              // rows per block (8 waves x 32)
#define RBLOCKS  (L_TOK / 32)  // 1024 refine blocks

#define ASCALE  -4194304.0f    // -2^22: A-fragment pre-scale (exact pow2)
#define ESCALE   2097152.0f    // 2^21 = 0.5*2^22 for esq
#define KBIAS_F  32768.0f      // 2^15 bias, folded into esqs at prep

typedef unsigned short ushort_t;
typedef __attribute__((ext_vector_type(8))) short bf16x8;
typedef __attribute__((ext_vector_type(4))) float f32x4;

// ---- ws layout (bytes) ----
#define WS_EHI   0u                                  // 2 MB   e bf16(RNE) permuted
#define WS_ESQ32 (2u<<20)                            // 64 KB  esq np-exact fp32
#define WS_ESQS  ((2u<<20) + (64u<<10))              // 64 KB  esq*2^21 + 2^15
#define WS_ESQ64 ((2u<<20) + (128u<<10))             // 128 KB esq fp64 (loss)
#define WS_CAND  ((2u<<20) + (256u<<10))             // 4 MB   cand[8][L][4] int
#define WS_PART  ((6u<<20) + (256u<<10))             // 8 KB   loss partials (1024 dbl)

__device__ __forceinline__ ushort_t bf16_rne(float v) {
  unsigned u = __float_as_uint(v);
  return (ushort_t)((u + 0x7fffu + ((u >> 16) & 1u)) >> 16);
}

// v_med3_u32: median(a,b,c). With b<=c this equals min(max(a,b),c) — the
// top-k insertion step; asked for directly since the compiler can't prove
// the K-ordering invariant.
__device__ __forceinline__ unsigned umed3(unsigned a, unsigned b, unsigned c) {
  unsigned d;
  asm("v_med3_u32 %0, %1, %2, %3" : "=v"(d) : "v"(a), "v"(b), "v"(c));
  return d;
}

// async global->LDS DMA, 16 B/lane (no VGPR round-trip; counts in vmcnt)
__device__ __forceinline__ void load_lds16(const ushort_t* g, ushort_t* l) {
  __builtin_amdgcn_global_load_lds(
      (const __attribute__((address_space(1))) void*)g,
      (__attribute__((address_space(3))) void*)l, 16, 0, 0);
}

// numpy pairwise_sum emulation for n=64 contiguous fp32 (scalar 8-acc path).
__device__ __forceinline__ float np_sum64(float a) {
  int j = threadIdx.x & 7;
  float r = __shfl(a, j);
  #pragma unroll
  for (int m = 1; m < 8; ++m) r += __shfl(a, j + 8 * m);
  float s0 = __shfl(r, 0), s1 = __shfl(r, 1), s2 = __shfl(r, 2), s3 = __shfl(r, 3);
  float s4 = __shfl(r, 4), s5 = __shfl(r, 5), s6 = __shfl(r, 6), s7 = __shfl(r, 7);
  return ((s0 + s1) + (s2 + s3)) + ((s4 + s5) + (s6 + s7));
}

// Fragment-permuted index (in ushorts) for element (n, k) — LDS staging order
// equals MFMA B-fragment consumption order (conflict-free ds_read_b128).
__device__ __forceinline__ int perm_off(int n, int k) {
  int tile = n >> 4, c = n & 15, s = k >> 5, q = (k >> 3) & 3, j = k & 7;
  return tile * 1024 + s * 512 + (q * 16 + c) * 8 + j;
}

// ---------------- kernel 1: prep embedding -----------------------------------
__global__ __launch_bounds__(256) void vq_prep_e(const float* __restrict__ e,
                                                 ushort_t* __restrict__ ehi,
                                                 float* __restrict__ esq32,
                                                 float* __restrict__ esqs,
                                                 double* __restrict__ esq64) {
  int wave = threadIdx.x >> 6, lane = threadIdx.x & 63;
  int row = blockIdx.x * 4 + wave;            // one wave per embedding row
  float v = e[(size_t)row * D_DIM + lane];
  ehi[perm_off(row, lane)] = bf16_rne(v);
  float esq = np_sum64(v * v);                // numpy-bit-exact sum(e*e, axis=1)
  double p = (double)v * (double)v;
  #pragma unroll
  for (int o = 32; o; o >>= 1) p += __shfl_xor(p, o);
  if (lane == 0) {
    esq32[row] = esq;                         // exact rescore
    esqs[row]  = esq * ESCALE + KBIAS_F;      // sieve MFMA C operand
    esq64[row] = p;                           // loss
  }
}

// ---------------- kernel 2: fused distance + per-row top-k sieve -------------
// grid = dim3(GCHUNKS, L/BROWS) = 1024 blocks, block = 512 (8 waves x 32 rows)
// Staging: async global_load_lds DMA, double-buffered 16 KB chunks — zero
// staging VGPRs, and the vmcnt(0) inside __syncthreads waits on loads issued
// a full compute phase earlier (no drain stall).  esq preloaded once (8 KB).
// A is pre-scaled by -2^22, esq*2^21+2^15 rides as the MFMA C operand, so
// acc == 2^22*d + 2^15 (positive by Cauchy-Schwarz: |dot|*2^22 < 24.7k < 2^15).
// Packed key: (trunc(acc) << 12) | (tile*16+c).  Per-lane top-2 -> per-row
// top-4 per 2048-chunk (np-winner missing needs >=4 sieve-better entries in
// its chunk within the ~8e-6 window — quartic-rare); refine resolves exactly.
__global__ __launch_bounds__(512, 8) void vq_argmin(const float* __restrict__ z,
                                                    const ushort_t* __restrict__ ehi,
                                                    const float* __restrict__ esqs,
                                                    int* __restrict__ cand) {
  __shared__ __align__(16) unsigned char smem[40960]; // 2x16KB ehi dbuf + 8KB esq
  ushort_t* s_buf = (ushort_t*)smem;                  // [2][8192] ushorts
  float*    s_esq = (float*)(smem + 32768);           // 2048 floats (whole NPB)

  const int tid = threadIdx.x;
  const int wave = tid >> 6, lane = tid & 63;
  const int q = lane >> 4, c = lane & 15;
  const int row0 = blockIdx.y * BROWS + wave * WROWS;
  const int nbase = blockIdx.x * NPB;

  // A fragments: two row-groups of 16, bf16(RNE) of -2^22*z in-register.
  // A layout: lane holds A[m=lane&15][k = q*8 + j (+32 for k-step 1)]
  bf16x8 zA[2][2];
  #pragma unroll
  for (int g = 0; g < 2; ++g) {
    const float* zr = z + (size_t)(row0 + g * 16 + c) * D_DIM;
    float4 a0 = *(const float4*)(zr + q * 8);
    float4 a1 = *(const float4*)(zr + q * 8 + 4);
    float4 a2 = *(const float4*)(zr + 32 + q * 8);
    float4 a3 = *(const float4*)(zr + 32 + q * 8 + 4);
    zA[g][0][0] = (short)bf16_rne(a0.x * ASCALE); zA[g][0][1] = (short)bf16_rne(a0.y * ASCALE);
    zA[g][0][2] = (short)bf16_rne(a0.z * ASCALE); zA[g][0][3] = (short)bf16_rne(a0.w * ASCALE);
    zA[g][0][4] = (short)bf16_rne(a1.x * ASCALE); zA[g][0][5] = (short)bf16_rne(a1.y * ASCALE);
    zA[g][0][6] = (short)bf16_rne(a1.z * ASCALE); zA[g][0][7] = (short)bf16_rne(a1.w * ASCALE);
    zA[g][1][0] = (short)bf16_rne(a2.x * ASCALE); zA[g][1][1] = (short)bf16_rne(a2.y * ASCALE);
    zA[g][1][2] = (short)bf16_rne(a2.z * ASCALE); zA[g][1][3] = (short)bf16_rne(a2.w * ASCALE);
    zA[g][1][4] = (short)bf16_rne(a3.x * ASCALE); zA[g][1][5] = (short)bf16_rne(a3.y * ASCALE);
    zA[g][1][6] = (short)bf16_rne(a3.z * ASCALE); zA[g][1][7] = (short)bf16_rne(a3.w * ASCALE);
  }

  // esq preload (once): 512 thr x float4 = 8 KB
  ((float4*)s_esq)[tid] = ((const float4*)(esqs + nbase))[tid];

  // per-(rowgroup g, acc row r) top-2 packed-key tracking (16 VGPRs),
  // invariant K0 <= K1 (init equal, preserved by med3 insertion)
  unsigned K0[2][4], K1[2][4];
  #pragma unroll
  for (int g = 0; g < 2; ++g)
    #pragma unroll
    for (int r = 0; r < 4; ++r) { K0[g][r] = 0xFFFFFFFFu; K1[g][r] = 0xFFFFFFFFu; }

  // prologue: async-stage chunk 0 into buf0 (2 DMA instructions per wave)
  {
    const ushort_t* g = ehi + (size_t)nbase * 64 + wave * 1024 + lane * 8;
    ushort_t* l = s_buf + wave * 1024 + lane * 8;
    load_lds16(g, l);
    load_lds16(g + 512, l + 512);
  }

  for (int cb = 0; cb < NCH; ++cb) {
    __syncthreads();   // vmcnt(0) waits loads(cb) — issued a compute-phase ago
    if (cb + 1 < NCH) {            // async-stage next chunk into the idle buffer
      int nnext = nbase + (cb + 1) * BN;
      const ushort_t* g = ehi + (size_t)nnext * 64 + wave * 1024 + lane * 8;
      ushort_t* l = s_buf + ((cb + 1) & 1) * 8192 + wave * 1024 + lane * 8;
      load_lds16(g, l);
      load_lds16(g + 512, l + 512);
    }
    const ushort_t* buf = s_buf + (cb & 1) * 8192;
    const float*    esqc = s_esq + cb * BN;

    #pragma unroll
    for (int t = 0; t < BN / 16; ++t) {
      const bf16x8 bh0 = *(const bf16x8*)(buf + t * 1024 + lane * 8);
      const bf16x8 bh1 = *(const bf16x8*)(buf + t * 1024 + 512 + lane * 8);
      float esqv = esqc[t * 16 + c];
      f32x4 cvec = {esqv, esqv, esqv, esqv};       // key bias rides in as C
      unsigned tcv = (((unsigned)(cb * 8 + t)) << 4) | (unsigned)c;  // n_local
      f32x4 acc0 = __builtin_amdgcn_mfma_f32_16x16x32_bf16(zA[0][0], bh0, cvec, 0, 0, 0);
      acc0 = __builtin_amdgcn_mfma_f32_16x16x32_bf16(zA[0][1], bh1, acc0, 0, 0, 0);
      f32x4 acc1 = __builtin_amdgcn_mfma_f32_16x16x32_bf16(zA[1][0], bh0, cvec, 0, 0, 0);
      acc1 = __builtin_amdgcn_mfma_f32_16x16x32_bf16(zA[1][1], bh1, acc1, 0, 0, 0);
      #pragma unroll
      for (int r = 0; r < 4; ++r) {
        unsigned pk = (((unsigned)acc0[r]) << 12) | tcv;   // cvt + lshl_or
        K1[0][r] = umed3(pk, K0[0][r], K1[0][r]);
        K0[0][r] = min(pk, K0[0][r]);
      }
      #pragma unroll
      for (int r = 0; r < 4; ++r) {
        unsigned pk = (((unsigned)acc1[r]) << 12) | tcv;
        K1[1][r] = umed3(pk, K0[1][r], K1[1][r]);
        K0[1][r] = min(pk, K0[1][r]);
      }
    }
  }

  // merge 16 lanes' top-2 -> per-row top-4 for this chunk
  __syncthreads();
  unsigned* s_k = (unsigned*)smem;             // [256 rows][16 c][2] = 32 KB
  #pragma unroll
  for (int g = 0; g < 2; ++g)
    #pragma unroll
    for (int r = 0; r < 4; ++r) {
      int rowidx = wave * WROWS + g * 16 + q * 4 + r;  // C layout: row = q*4 + reg
      int base = (rowidx * 16 + c) * 2;
      s_k[base + 0] = K0[g][r]; s_k[base + 1] = K1[g][r];
    }
  __syncthreads();
  if (tid < BROWS) {
    unsigned M0 = 0xFFFFFFFFu, M1 = 0xFFFFFFFFu, M2 = 0xFFFFFFFFu, M3 = 0xFFFFFFFFu;
    const uint4* sv = (const uint4*)(s_k + tid * 32);
    #pragma unroll
    for (int v4 = 0; v4 < 8; ++v4) {
      uint4 kk = sv[v4];
      unsigned vals[4] = {kk.x, kk.y, kk.z, kk.w};
      #pragma unroll
      for (int u = 0; u < 4; ++u) {
        unsigned v = vals[u];
        M3 = umed3(v, M2, M3);
        M2 = umed3(v, M1, M2);
        M1 = umed3(v, M0, M1);
        M0 = min(v, M0);
      }
    }
    int grow = blockIdx.y * BROWS + tid;
    int* cp = cand + ((size_t)blockIdx.x * L_TOK + grow) * 4;
    cp[0] = (int)(nbase + (M0 & 4095u)); cp[1] = (int)(nbase + (M1 & 4095u));
    cp[2] = (int)(nbase + (M2 & 4095u)); cp[3] = (int)(nbase + (M3 & 4095u));
  }
}

// ------- kernel 3: np-fp32-exact rescore of 32 candidates, outputs ----------
// grid = L/32 blocks, block 512 (8 waves); each wave: 4 rows, one row per
// iter with 32 cand-groups x 2 lanes.  fp64 dot in two passes of 4 float4
// (halves live VGPRs) over 4 independent accumulators.
__global__ __launch_bounds__(512, 6) void vq_refine(const float* __restrict__ z,
                                                    const float* __restrict__ e,
                                                    const float* __restrict__ esq32,
                                                    const double* __restrict__ esq64,
                                                    const int* __restrict__ cand,
                                                    float* __restrict__ out,
                                                    double* __restrict__ partials) {
  const int tid = threadIdx.x;
  const int wave = tid >> 6, lane = tid & 63;
  const int g = lane >> 1, s = lane & 1;      // 32 cand-groups x 2 lanes
  __shared__ double sp[8];
  double wl = 0.0;
  for (int it = 0; it < 4; ++it) {
    int row = blockIdx.x * 32 + wave * 4 + it;
    float zf = z[(size_t)row * D_DIM + lane];
    float zsqv = np_sum64(zf * zf);            // numpy-bit-exact sum(z*z, axis=1)
    double zp64 = (double)zf * (double)zf;
    #pragma unroll
    for (int o = 32; o; o >>= 1) zp64 += __shfl_xor(zp64, o);
    int idx = cand[((size_t)(g >> 2) * L_TOK + row) * 4 + (g & 3)];
    // fp64 dot over 32 elements/lane, 4 independent accumulators
    const float4* ep = (const float4*)(e + (size_t)idx * D_DIM + s * 32);
    const float4* zp = (const float4*)(z + (size_t)row * D_DIM + s * 32);
    double da = 0.0, db = 0.0, dc = 0.0, dd = 0.0;
    #pragma unroll
    for (int h = 0; h < 2; ++h) {
      float4 e0 = ep[h * 4 + 0], e1 = ep[h * 4 + 1];
      float4 e2 = ep[h * 4 + 2], e3 = ep[h * 4 + 3];
      float4 z0 = zp[h * 4 + 0], z1 = zp[h * 4 + 1];
      float4 z2 = zp[h * 4 + 2], z3 = zp[h * 4 + 3];
      da = fma((double)e0.x, (double)z0.x, da);
      da = fma((double)e0.y, (double)z0.y, da);
      da = fma((double)e0.z, (double)z0.z, da);
      da = fma((double)e0.w, (double)z0.w, da);
      db = fma((double)e1.x, (double)z1.x, db);
      db = fma((double)e1.y, (double)z1.y, db);
      db = fma((double)e1.z, (double)z1.z, db);
      db = fma((double)e1.w, (double)z1.w, db);
      dc = fma((double)e2.x, (double)z2.x, dc);
      dc = fma((double)e2.y, (double)z2.y, dc);
      dc = fma((double)e2.z, (double)z2.z, dc);
      dc = fma((double)e2.w, (double)z2.w, dc);
      dd = fma((double)e3.x, (double)z3.x, dd);
      dd = fma((double)e3.y, (double)z3.y, dd);
      dd = fma((double)e3.z, (double)z3.z, dd);
      dd = fma((double)e3.w, (double)z3.w, dd);
    }
    double dot = (da + db) + (dc + dd);
    dot += __shfl_xor(dot, 1);
    // emulate np fp32: d = fl32( fl32(zsq + esq) - fl32(2*dot) )
    float t2 = (float)(2.0 * dot);
    float T1 = zsqv + esq32[idx];
    float d  = T1 - t2;                        // d ~ 64 > 0: bits are monotone
    unsigned long long key = ((unsigned long long)__float_as_uint(d) << 14)
                           | (unsigned)idx;    // tie -> lower idx (np.argmin)
    double dotw = dot;
    #pragma unroll
    for (int o = 2; o <= 32; o <<= 1) {
      unsigned long long ok = __shfl_xor(key, o);
      double od = __shfl_xor(dotw, o);
      bool take = ok < key;
      key  = take ? ok : key;
      dotw = take ? od : dotw;
    }
    int win = (int)(key & 16383u);
    // outputs (element layout; whole wave)
    float be = e[(size_t)win * D_DIM + lane];
    out[(size_t)row * D_DIM + lane] = zf + (be - zf);   // fp32 op-order ST
    if (lane == 0) {
      out[(size_t)L_TOK * D_DIM + 1 + row] = (float)win;
      wl += zp64 + esq64[win] - 2.0 * dotw;             // ||z - e_win||^2 (fp64)
    }
  }
  if (lane == 0) sp[wave] = wl;
  __syncthreads();
  if (tid == 0) {
    double t = 0.0;
    #pragma unroll
    for (int w = 0; w < 8; ++w) t += sp[w];
    partials[blockIdx.x] = t;
  }
}

// ---------------- kernel 4: finalize loss (1024 partials) --------------------
__global__ __launch_bounds__(512) void vq_loss(const double* __restrict__ partials,
                                               float* __restrict__ out) {
  int tid = threadIdx.x;
  double v = partials[tid] + partials[tid + 512];
  #pragma unroll
  for (int o = 32; o; o >>= 1) v += __shfl_xor(v, o);
  __shared__ double sp[8];
  if ((tid & 63) == 0) sp[tid >> 6] = v;
  __syncthreads();
  if (tid == 0) {
    double tot = 0.0;
    #pragma unroll
    for (int w = 0; w < 8; ++w) tot += sp[w];
    // loss = beta*mean + mean = 1.25 * mean((z_q - z)^2)
    out[(size_t)L_TOK * D_DIM] = (float)(1.25 * tot / (double)((size_t)L_TOK * D_DIM));
  }
}

extern "C" void kernel_launch(void* const* d_in, const int* in_sizes, int n_in,
                              void* d_out, int out_size, void* d_ws, size_t ws_size,
                              hipStream_t stream) {
  const float* z = (const float*)d_in[0];       // (32768, 64) fp32
  const float* e = (const float*)d_in[1];       // (16384, 64) fp32
  float* out = (float*)d_out;                   // [z_q_st | loss | indices-as-f32]
  char* ws = (char*)d_ws;                       // needs ~6.3 MB

  ushort_t* ehi   = (ushort_t*)(ws + WS_EHI);
  float*    esq32 = (float*)(ws + WS_ESQ32);
  float*    esqs  = (float*)(ws + WS_ESQS);
  double*   esq64 = (double*)(ws + WS_ESQ64);
  int*      cand  = (int*)(ws + WS_CAND);
  double*   parts = (double*)(ws + WS_PART);

  vq_prep_e<<<NE / 4, 256, 0, stream>>>(e, ehi, esq32, esqs, esq64);
  vq_argmin<<<dim3(GCHUNKS, L_TOK / BROWS), 512, 0, stream>>>(z, ehi, esqs, cand);
  vq_refine<<<RBLOCKS, 512, 0, stream>>>(z, e, esq32, esq64, cand, out, parts);
  vq_loss<<<1, 512, 0, stream>>>(parts, out);
}

// Round 12
// 205.150 us; speedup vs baseline: 1.3166x; 1.1834x over previous
//
#include <hip/hip_runtime.h>
#include <cstdint>
#include <cstddef>

// Problem constants (VectorQuantizer: L=32768, D=64, N_E=16384, beta=0.25)
#define L_TOK 32768
#define D_DIM 64
#define NE    16384
#define GCHUNKS 8              // N split across grid (8 -> 8192 waves total)
#define NPB   (NE / GCHUNKS)   // 2048 n per block
#define BN    128              // n per LDS stage chunk (double-buffered)
#define NCH   (NPB / BN)       // 16 chunks per block
#define WROWS 32               // rows per wave (2 MFMA row-groups)
#define BROWS 256              // rows per block (8 waves x 32)
#define RBLOCKS  (L_TOK / 32)  // 1024 refine blocks

#define ASCALE  -4194304.0f    // -2^22: A-fragment pre-scale (exact pow2)
#define ESCALE   2097152.0f    // 2^21 = 0.5*2^22 for esq
#define KBIAS_F  32768.0f      // 2^15 bias, folded into esqs at prep
#define QDELTA   160u          // refine prune window in qi units (3.8e-5 in d)

typedef unsigned short ushort_t;
typedef __attribute__((ext_vector_type(8))) short bf16x8;
typedef __attribute__((ext_vector_type(4))) float f32x4;

// ---- ws layout (bytes) ----
#define WS_EHI   0u                                  // 2 MB   e bf16(RNE) permuted
#define WS_ESQ32 (2u<<20)                            // 64 KB  esq np-exact fp32
#define WS_ESQS  ((2u<<20) + (64u<<10))              // 64 KB  esq*2^21 + 2^15
#define WS_ESQ64 ((2u<<20) + (128u<<10))             // 128 KB esq fp64 (loss)
#define WS_CAND  ((2u<<20) + (256u<<10))             // 4 MB   candkeys[8][L][4] u32
#define WS_PART  ((6u<<20) + (256u<<10))             // 8 KB   loss partials (1024 dbl)

__device__ __forceinline__ ushort_t bf16_rne(float v) {
  unsigned u = __float_as_uint(v);
  return (ushort_t)((u + 0x7fffu + ((u >> 16) & 1u)) >> 16);
}

// v_med3_u32: median(a,b,c). With b<=c this equals min(max(a,b),c) — the
// top-k insertion step; asked for directly since the compiler can't prove
// the K-ordering invariant.
__device__ __forceinline__ unsigned umed3(unsigned a, unsigned b, unsigned c) {
  unsigned d;
  asm("v_med3_u32 %0, %1, %2, %3" : "=v"(d) : "v"(a), "v"(b), "v"(c));
  return d;
}

// async global->LDS DMA, 16 B/lane (no VGPR round-trip; counts in vmcnt)
__device__ __forceinline__ void load_lds16(const ushort_t* g, ushort_t* l) {
  __builtin_amdgcn_global_load_lds(
      (const __attribute__((address_space(1))) void*)g,
      (__attribute__((address_space(3))) void*)l, 16, 0, 0);
}

// numpy pairwise_sum emulation for n=64 contiguous fp32 (scalar 8-acc path).
__device__ __forceinline__ float np_sum64(float a) {
  int j = threadIdx.x & 7;
  float r = __shfl(a, j);
  #pragma unroll
  for (int m = 1; m < 8; ++m) r += __shfl(a, j + 8 * m);
  float s0 = __shfl(r, 0), s1 = __shfl(r, 1), s2 = __shfl(r, 2), s3 = __shfl(r, 3);
  float s4 = __shfl(r, 4), s5 = __shfl(r, 5), s6 = __shfl(r, 6), s7 = __shfl(r, 7);
  return ((s0 + s1) + (s2 + s3)) + ((s4 + s5) + (s6 + s7));
}

// Fragment-permuted index (in ushorts) for element (n, k) — LDS staging order
// equals MFMA B-fragment consumption order (conflict-free ds_read_b128).
__device__ __forceinline__ int perm_off(int n, int k) {
  int tile = n >> 4, c = n & 15, s = k >> 5, q = (k >> 3) & 3, j = k & 7;
  return tile * 1024 + s * 512 + (q * 16 + c) * 8 + j;
}

// ---------------- kernel 1: prep embedding -----------------------------------
__global__ __launch_bounds__(256) void vq_prep_e(const float* __restrict__ e,
                                                 ushort_t* __restrict__ ehi,
                                                 float* __restrict__ esq32,
                                                 float* __restrict__ esqs,
                                                 double* __restrict__ esq64) {
  int wave = threadIdx.x >> 6, lane = threadIdx.x & 63;
  int row = blockIdx.x * 4 + wave;            // one wave per embedding row
  float v = e[(size_t)row * D_DIM + lane];
  ehi[perm_off(row, lane)] = bf16_rne(v);
  float esq = np_sum64(v * v);                // numpy-bit-exact sum(e*e, axis=1)
  double p = (double)v * (double)v;
  #pragma unroll
  for (int o = 32; o; o >>= 1) p += __shfl_xor(p, o);
  if (lane == 0) {
    esq32[row] = esq;                         // exact rescore
    esqs[row]  = esq * ESCALE + KBIAS_F;      // sieve MFMA C operand
    esq64[row] = p;                           // loss
  }
}

// ---------------- kernel 2: fused distance + per-row top-k sieve -------------
// grid = dim3(GCHUNKS, L/BROWS) = 1024 blocks, block = 512 (8 waves x 32 rows)
// Staging: async global_load_lds DMA, double-buffered 16 KB chunks.
// acc == 2^22*d + 2^15 via pre-scaled A and esq-as-C (positive by C-S bound).
// Packed key: (trunc(acc) << 12) | (tile*16+c).  Per-lane top-2 -> per-row
// top-4 RAW KEYS per 2048-chunk written to candkeys (refine prunes on qi).
__global__ __launch_bounds__(512, 8) void vq_argmin(const float* __restrict__ z,
                                                    const ushort_t* __restrict__ ehi,
                                                    const float* __restrict__ esqs,
                                                    unsigned* __restrict__ candk) {
  __shared__ __align__(16) unsigned char smem[40960]; // dbuf 2x16KB + 8KB esq;
  ushort_t* s_buf = (ushort_t*)smem;                  // merge: 256x36 words (36.9KB)
  float*    s_esq = (float*)(smem + 32768);           // 2048 floats (whole NPB)

  const int tid = threadIdx.x;
  const int wave = tid >> 6, lane = tid & 63;
  const int q = lane >> 4, c = lane & 15;
  const int row0 = blockIdx.y * BROWS + wave * WROWS;
  const int nbase = blockIdx.x * NPB;

  // A fragments: two row-groups of 16, bf16(RNE) of -2^22*z in-register.
  bf16x8 zA[2][2];
  #pragma unroll
  for (int g = 0; g < 2; ++g) {
    const float* zr = z + (size_t)(row0 + g * 16 + c) * D_DIM;
    float4 a0 = *(const float4*)(zr + q * 8);
    float4 a1 = *(const float4*)(zr + q * 8 + 4);
    float4 a2 = *(const float4*)(zr + 32 + q * 8);
    float4 a3 = *(const float4*)(zr + 32 + q * 8 + 4);
    zA[g][0][0] = (short)bf16_rne(a0.x * ASCALE); zA[g][0][1] = (short)bf16_rne(a0.y * ASCALE);
    zA[g][0][2] = (short)bf16_rne(a0.z * ASCALE); zA[g][0][3] = (short)bf16_rne(a0.w * ASCALE);
    zA[g][0][4] = (short)bf16_rne(a1.x * ASCALE); zA[g][0][5] = (short)bf16_rne(a1.y * ASCALE);
    zA[g][0][6] = (short)bf16_rne(a1.z * ASCALE); zA[g][0][7] = (short)bf16_rne(a1.w * ASCALE);
    zA[g][1][0] = (short)bf16_rne(a2.x * ASCALE); zA[g][1][1] = (short)bf16_rne(a2.y * ASCALE);
    zA[g][1][2] = (short)bf16_rne(a2.z * ASCALE); zA[g][1][3] = (short)bf16_rne(a2.w * ASCALE);
    zA[g][1][4] = (short)bf16_rne(a3.x * ASCALE); zA[g][1][5] = (short)bf16_rne(a3.y * ASCALE);
    zA[g][1][6] = (short)bf16_rne(a3.z * ASCALE); zA[g][1][7] = (short)bf16_rne(a3.w * ASCALE);
  }

  // esq preload (once): 512 thr x float4 = 8 KB
  ((float4*)s_esq)[tid] = ((const float4*)(esqs + nbase))[tid];

  // per-(rowgroup g, acc row r) top-2 packed-key tracking, K0 <= K1 invariant
  unsigned K0[2][4], K1[2][4];
  #pragma unroll
  for (int g = 0; g < 2; ++g)
    #pragma unroll
    for (int r = 0; r < 4; ++r) { K0[g][r] = 0xFFFFFFFFu; K1[g][r] = 0xFFFFFFFFu; }

  // prologue: async-stage chunk 0 into buf0 (2 DMA instructions per wave)
  {
    const ushort_t* g = ehi + (size_t)nbase * 64 + wave * 1024 + lane * 8;
    ushort_t* l = s_buf + wave * 1024 + lane * 8;
    load_lds16(g, l);
    load_lds16(g + 512, l + 512);
  }

  for (int cb = 0; cb < NCH; ++cb) {
    __syncthreads();   // vmcnt(0) waits loads(cb) — issued a compute-phase ago
    if (cb + 1 < NCH) {            // async-stage next chunk into the idle buffer
      int nnext = nbase + (cb + 1) * BN;
      const ushort_t* g = ehi + (size_t)nnext * 64 + wave * 1024 + lane * 8;
      ushort_t* l = s_buf + ((cb + 1) & 1) * 8192 + wave * 1024 + lane * 8;
      load_lds16(g, l);
      load_lds16(g + 512, l + 512);
    }
    const ushort_t* buf = s_buf + (cb & 1) * 8192;
    const float*    esqc = s_esq + cb * BN;

    #pragma unroll
    for (int t = 0; t < BN / 16; ++t) {
      const bf16x8 bh0 = *(const bf16x8*)(buf + t * 1024 + lane * 8);
      const bf16x8 bh1 = *(const bf16x8*)(buf + t * 1024 + 512 + lane * 8);
      float esqv = esqc[t * 16 + c];
      f32x4 cvec = {esqv, esqv, esqv, esqv};       // key bias rides in as C
      unsigned tcv = (((unsigned)(cb * 8 + t)) << 4) | (unsigned)c;  // n_local
      f32x4 acc0 = __builtin_amdgcn_mfma_f32_16x16x32_bf16(zA[0][0], bh0, cvec, 0, 0, 0);
      acc0 = __builtin_amdgcn_mfma_f32_16x16x32_bf16(zA[0][1], bh1, acc0, 0, 0, 0);
      f32x4 acc1 = __builtin_amdgcn_mfma_f32_16x16x32_bf16(zA[1][0], bh0, cvec, 0, 0, 0);
      acc1 = __builtin_amdgcn_mfma_f32_16x16x32_bf16(zA[1][1], bh1, acc1, 0, 0, 0);
      #pragma unroll
      for (int r = 0; r < 4; ++r) {
        unsigned pk = (((unsigned)acc0[r]) << 12) | tcv;   // cvt + lshl_or
        K1[0][r] = umed3(pk, K0[0][r], K1[0][r]);
        K0[0][r] = min(pk, K0[0][r]);
      }
      #pragma unroll
      for (int r = 0; r < 4; ++r) {
        unsigned pk = (((unsigned)acc1[r]) << 12) | tcv;
        K1[1][r] = umed3(pk, K0[1][r], K1[1][r]);
        K0[1][r] = min(pk, K0[1][r]);
      }
    }
  }

  // merge 16 lanes' top-2 -> per-row top-4 keys (row stride 36 words: breaks
  // the all-lanes-same-bank-group pattern of stride 32)
  __syncthreads();
  unsigned* s_k = (unsigned*)smem;             // [256 rows][36 words]
  #pragma unroll
  for (int g = 0; g < 2; ++g)
    #pragma unroll
    for (int r = 0; r < 4; ++r) {
      int rowidx = wave * WROWS + g * 16 + q * 4 + r;  // C layout: row = q*4 + reg
      int base = rowidx * 36 + c * 2;
      s_k[base + 0] = K0[g][r]; s_k[base + 1] = K1[g][r];
    }
  __syncthreads();
  if (tid < BROWS) {
    unsigned M0 = 0xFFFFFFFFu, M1 = 0xFFFFFFFFu, M2 = 0xFFFFFFFFu, M3 = 0xFFFFFFFFu;
    const uint4* sv = (const uint4*)(s_k + tid * 36);
    #pragma unroll
    for (int v4 = 0; v4 < 8; ++v4) {
      uint4 kk = sv[v4];
      unsigned vals[4] = {kk.x, kk.y, kk.z, kk.w};
      #pragma unroll
      for (int u = 0; u < 4; ++u) {
        unsigned v = vals[u];
        M3 = umed3(v, M2, M3);
        M2 = umed3(v, M1, M2);
        M1 = umed3(v, M0, M1);
        M0 = min(v, M0);
      }
    }
    int grow = blockIdx.y * BROWS + tid;
    unsigned* cp = candk + ((size_t)blockIdx.x * L_TOK + grow) * 4;
    cp[0] = M0; cp[1] = M1; cp[2] = M2; cp[3] = M3;    // raw keys (qi<<12|n_local)
  }
}

// ------- kernel 3: key-pruned np-fp32-exact rescore, outputs ----------------
// grid = L/32 blocks, block 512 (8 waves); wave: 4 rows, 32 cand-groups x 2
// lanes.  Only candidates with qi <= min_qi + QDELTA are rescored (typically
// 1-2): the np-winner's qi is provably within ~84 qi of the candidate min
// (np-fp32 rounding 1.5e-5 + 5-sigma sieve noise), QDELTA=160 doubles that.
__global__ __launch_bounds__(512, 6) void vq_refine(const float* __restrict__ z,
                                                    const float* __restrict__ e,
                                                    const float* __restrict__ esq32,
                                                    const double* __restrict__ esq64,
                                                    const unsigned* __restrict__ candk,
                                                    float* __restrict__ out,
                                                    double* __restrict__ partials) {
  const int tid = threadIdx.x;
  const int wave = tid >> 6, lane = tid & 63;
  const int g = lane >> 1, s = lane & 1;      // 32 cand-groups x 2 lanes
  __shared__ double sp[8];
  double wl = 0.0;
  for (int it = 0; it < 4; ++it) {
    int row = blockIdx.x * 32 + wave * 4 + it;
    float zf = z[(size_t)row * D_DIM + lane];
    float zsqv = np_sum64(zf * zf);            // numpy-bit-exact sum(z*z, axis=1)
    double zp64 = (double)zf * (double)zf;
    #pragma unroll
    for (int o = 32; o; o >>= 1) zp64 += __shfl_xor(zp64, o);
    unsigned k = candk[((size_t)(g >> 2) * L_TOK + row) * 4 + (g & 3)];
    unsigned qi = k >> 12;
    unsigned n  = ((unsigned)(g >> 2) * (unsigned)NPB) + (k & 4095u);
    unsigned gkey = (qi << 14) | n;            // globally ordered (qi, then n)
    unsigned m = gkey;
    #pragma unroll
    for (int o = 1; o < 64; o <<= 1) m = min(m, (unsigned)__shfl_xor((int)m, o));
    unsigned minqi = m >> 14;
    bool part = qi <= minqi + QDELTA;
    unsigned long long key = ~0ull;
    double dotw = 0.0;
    if (part) {                                // both lanes of a pair agree
      const float4* ep = (const float4*)(e + (size_t)n * D_DIM + s * 32);
      const float4* zp = (const float4*)(z + (size_t)row * D_DIM + s * 32);
      double da = 0.0, db = 0.0, dc = 0.0, dd = 0.0;
      #pragma unroll
      for (int h = 0; h < 2; ++h) {
        float4 e0 = ep[h * 4 + 0], e1 = ep[h * 4 + 1];
        float4 e2 = ep[h * 4 + 2], e3 = ep[h * 4 + 3];
        float4 z0 = zp[h * 4 + 0], z1 = zp[h * 4 + 1];
        float4 z2 = zp[h * 4 + 2], z3 = zp[h * 4 + 3];
        da = fma((double)e0.x, (double)z0.x, da); da = fma((double)e0.y, (double)z0.y, da);
        da = fma((double)e0.z, (double)z0.z, da); da = fma((double)e0.w, (double)z0.w, da);
        db = fma((double)e1.x, (double)z1.x, db); db = fma((double)e1.y, (double)z1.y, db);
        db = fma((double)e1.z, (double)z1.z, db); db = fma((double)e1.w, (double)z1.w, db);
        dc = fma((double)e2.x, (double)z2.x, dc); dc = fma((double)e2.y, (double)z2.y, dc);
        dc = fma((double)e2.z, (double)z2.z, dc); dc = fma((double)e2.w, (double)z2.w, dc);
        dd = fma((double)e3.x, (double)z3.x, dd); dd = fma((double)e3.y, (double)z3.y, dd);
        dd = fma((double)e3.z, (double)z3.z, dd); dd = fma((double)e3.w, (double)z3.w, dd);
      }
      double dot = (da + db) + (dc + dd);
      dot += __shfl_xor(dot, 1);               // pair-mate has same `part`
      // emulate np fp32: d = fl32( fl32(zsq + esq) - fl32(2*dot) )
      float t2 = (float)(2.0 * dot);
      float T1 = zsqv + esq32[n];
      float d  = T1 - t2;                      // d ~ 64 > 0: bits are monotone
      key  = ((unsigned long long)__float_as_uint(d) << 14) | n;  // tie: lower n
      dotw = dot;
    }
    #pragma unroll
    for (int o = 2; o <= 32; o <<= 1) {        // pair-mates equal; 5 steps
      unsigned long long ok = __shfl_xor(key, o);
      double od = __shfl_xor(dotw, o);
      bool take = ok < key;
      key  = take ? ok : key;
      dotw = take ? od : dotw;
    }
    int win = (int)(key & 16383u);
    // outputs (element layout; whole wave)
    float be = e[(size_t)win * D_DIM + lane];
    out[(size_t)row * D_DIM + lane] = zf + (be - zf);   // fp32 op-order ST
    if (lane == 0) {
      out[(size_t)L_TOK * D_DIM + 1 + row] = (float)win;
      wl += zp64 + esq64[win] - 2.0 * dotw;             // ||z - e_win||^2 (fp64)
    }
  }
  if (lane == 0) sp[wave] = wl;
  __syncthreads();
  if (tid == 0) {
    double t = 0.0;
    #pragma unroll
    for (int w = 0; w < 8; ++w) t += sp[w];
    partials[blockIdx.x] = t;
  }
}

// ---------------- kernel 4: finalize loss (1024 partials) --------------------
__global__ __launch_bounds__(512) void vq_loss(const double* __restrict__ partials,
                                               float* __restrict__ out) {
  int tid = threadIdx.x;
  double v = partials[tid] + partials[tid + 512];
  #pragma unroll
  for (int o = 32; o; o >>= 1) v += __shfl_xor(v, o);
  __shared__ double sp[8];
  if ((tid & 63) == 0) sp[tid >> 6] = v;
  __syncthreads();
  if (tid == 0) {
    double tot = 0.0;
    #pragma unroll
    for (int w = 0; w < 8; ++w) tot += sp[w];
    // loss = beta*mean + mean = 1.25 * mean((z_q - z)^2)
    out[(size_t)L_TOK * D_DIM] = (float)(1.25 * tot / (double)((size_t)L_TOK * D_DIM));
  }
}

extern "C" void kernel_launch(void* const* d_in, const int* in_sizes, int n_in,
                              void* d_out, int out_size, void* d_ws, size_t ws_size,
                              hipStream_t stream) {
  const float* z = (const float*)d_in[0];       // (32768, 64) fp32
  const float* e = (const float*)d_in[1];       // (16384, 64) fp32
  float* out = (float*)d_out;                   // [z_q_st | loss | indices-as-f32]
  char* ws = (char*)d_ws;                       // needs ~6.3 MB

  ushort_t* ehi   = (ushort_t*)(ws + WS_EHI);
  float*    esq32 = (float*)(ws + WS_ESQ32);
  float*    esqs  = (float*)(ws + WS_ESQS);
  double*   esq64 = (double*)(ws + WS_ESQ64);
  unsigned* candk = (unsigned*)(ws + WS_CAND);
  double*   parts = (double*)(ws + WS_PART);

  vq_prep_e<<<NE / 4, 256, 0, stream>>>(e, ehi, esq32, esqs, esq64);
  vq_argmin<<<dim3(GCHUNKS, L_TOK / BROWS), 512, 0, stream>>>(z, ehi, esqs, candk);
  vq_refine<<<RBLOCKS, 512, 0, stream>>>(z, e, esq32, esq64, candk, out, parts);
  vq_loss<<<1, 512, 0, stream>>>(parts, out);
}

// Round 13
// 203.629 us; speedup vs baseline: 1.3265x; 1.0075x over previous
//
#include <hip/hip_runtime.h>
#include <cstdint>
#include <cstddef>

// Problem constants (VectorQuantizer: L=32768, D=64, N_E=16384, beta=0.25)
#define L_TOK 32768
#define D_DIM 64
#define NE    16384
#define GCHUNKS 8              // N split across grid (8 -> 8192 waves total)
#define NPB   (NE / GCHUNKS)   // 2048 n per block
#define BN    128              // n per LDS stage chunk (double-buffered)
#define NCH   (NPB / BN)       // 16 chunks per block
#define WROWS 32               // rows per wave (2 MFMA row-groups)
#define BROWS 256              // rows per block (8 waves x 32)
#define RBLOCKS  (L_TOK / 32)  // 1024 refine blocks
#define EBLK  (NE / 4)         // prep blocks doing e rows
#define ZBLK  (L_TOK / 4)      // prep blocks doing z rows

#define ASCALE  -4194304.0f    // -2^22: A-fragment pre-scale (exact pow2)
#define ESCALE   2097152.0f    // 2^21 = 0.5*2^22 for esq
#define KBIAS_F  32768.0f      // 2^15 bias, folded into esqs at prep
#define QDELTA   160u          // refine prune window in qi units (3.8e-5 in d)

typedef unsigned short ushort_t;
typedef __attribute__((ext_vector_type(8))) short bf16x8;
typedef __attribute__((ext_vector_type(4))) float f32x4;

// ---- ws layout (bytes) ----
#define WS_EHI   0u                                  // 2 MB   e bf16(RNE) permuted
#define WS_ESQ32 (2u<<20)                            // 64 KB  esq np-exact fp32
#define WS_ESQS  ((2u<<20) + (64u<<10))              // 64 KB  esq*2^21 + 2^15
#define WS_ZSQ32 ((2u<<20) + (128u<<10))             // 128 KB zsq np-exact fp32
#define WS_CAND  ((2u<<20) + (256u<<10))             // 4 MB   candkeys[L][8][4] u32
#define WS_PART  ((6u<<20) + (256u<<10))             // 8 KB   loss partials (1024 dbl)

__device__ __forceinline__ ushort_t bf16_rne(float v) {
  unsigned u = __float_as_uint(v);
  return (ushort_t)((u + 0x7fffu + ((u >> 16) & 1u)) >> 16);
}

// v_med3_u32: median(a,b,c). With b<=c this equals min(max(a,b),c) — the
// top-k insertion step; asked for directly since the compiler can't prove
// the K-ordering invariant.
__device__ __forceinline__ unsigned umed3(unsigned a, unsigned b, unsigned c) {
  unsigned d;
  asm("v_med3_u32 %0, %1, %2, %3" : "=v"(d) : "v"(a), "v"(b), "v"(c));
  return d;
}

// async global->LDS DMA, 16 B/lane (no VGPR round-trip; counts in vmcnt)
__device__ __forceinline__ void load_lds16(const ushort_t* g, ushort_t* l) {
  __builtin_amdgcn_global_load_lds(
      (const __attribute__((address_space(1))) void*)g,
      (__attribute__((address_space(3))) void*)l, 16, 0, 0);
}

// numpy pairwise_sum emulation for n=64 contiguous fp32 (scalar 8-acc path).
__device__ __forceinline__ float np_sum64(float a) {
  int j = threadIdx.x & 7;
  float r = __shfl(a, j);
  #pragma unroll
  for (int m = 1; m < 8; ++m) r += __shfl(a, j + 8 * m);
  float s0 = __shfl(r, 0), s1 = __shfl(r, 1), s2 = __shfl(r, 2), s3 = __shfl(r, 3);
  float s4 = __shfl(r, 4), s5 = __shfl(r, 5), s6 = __shfl(r, 6), s7 = __shfl(r, 7);
  return ((s0 + s1) + (s2 + s3)) + ((s4 + s5) + (s6 + s7));
}

// Fragment-permuted index (in ushorts) for element (n, k) — LDS staging order
// equals MFMA B-fragment consumption order (conflict-free ds_read_b128).
__device__ __forceinline__ int perm_off(int n, int k) {
  int tile = n >> 4, c = n & 15, s = k >> 5, q = (k >> 3) & 3, j = k & 7;
  return tile * 1024 + s * 512 + (q * 16 + c) * 8 + j;
}

// ---------------- kernel 1: combined prep (e rows, then z rows) --------------
__global__ __launch_bounds__(256) void vq_prep(const float* __restrict__ e,
                                               const float* __restrict__ z,
                                               ushort_t* __restrict__ ehi,
                                               float* __restrict__ esq32,
                                               float* __restrict__ esqs,
                                               float* __restrict__ zsq32) {
  int wave = threadIdx.x >> 6, lane = threadIdx.x & 63;
  if (blockIdx.x < EBLK) {
    int row = blockIdx.x * 4 + wave;          // one wave per embedding row
    float v = e[(size_t)row * D_DIM + lane];
    ehi[perm_off(row, lane)] = bf16_rne(v);
    float esq = np_sum64(v * v);              // numpy-bit-exact sum(e*e, axis=1)
    if (lane == 0) {
      esq32[row] = esq;                       // exact rescore
      esqs[row]  = esq * ESCALE + KBIAS_F;    // sieve MFMA C operand
    }
  } else {
    int row = (blockIdx.x - EBLK) * 4 + wave; // one wave per z row
    float v = z[(size_t)row * D_DIM + lane];
    float s = np_sum64(v * v);                // numpy-bit-exact sum(z*z, axis=1)
    if (lane == 0) zsq32[row] = s;
  }
}

// ---------------- kernel 2: fused distance + per-row top-k sieve -------------
// grid = dim3(GCHUNKS, L/BROWS) = 1024 blocks, block = 512 (8 waves x 32 rows)
// Staging: async global_load_lds DMA, double-buffered 16 KB chunks.
// acc == 2^22*d + 2^15 via pre-scaled A and esq-as-C (positive by C-S bound).
// Packed key: (trunc(acc) << 12) | (tile*16+c).  Per-lane top-2 -> per-row
// top-4 RAW KEYS per 2048-chunk written to candk[row][chunk][4].
__global__ __launch_bounds__(512, 8) void vq_argmin(const float* __restrict__ z,
                                                    const ushort_t* __restrict__ ehi,
                                                    const float* __restrict__ esqs,
                                                    unsigned* __restrict__ candk) {
  __shared__ __align__(16) unsigned char smem[40960]; // dbuf 2x16KB + 8KB esq;
  ushort_t* s_buf = (ushort_t*)smem;                  // merge: 256x36 words (36.9KB)
  float*    s_esq = (float*)(smem + 32768);           // 2048 floats (whole NPB)

  const int tid = threadIdx.x;
  const int wave = tid >> 6, lane = tid & 63;
  const int q = lane >> 4, c = lane & 15;
  const int row0 = blockIdx.y * BROWS + wave * WROWS;
  const int nbase = blockIdx.x * NPB;

  // A fragments: two row-groups of 16, bf16(RNE) of -2^22*z in-register.
  bf16x8 zA[2][2];
  #pragma unroll
  for (int g = 0; g < 2; ++g) {
    const float* zr = z + (size_t)(row0 + g * 16 + c) * D_DIM;
    float4 a0 = *(const float4*)(zr + q * 8);
    float4 a1 = *(const float4*)(zr + q * 8 + 4);
    float4 a2 = *(const float4*)(zr + 32 + q * 8);
    float4 a3 = *(const float4*)(zr + 32 + q * 8 + 4);
    zA[g][0][0] = (short)bf16_rne(a0.x * ASCALE); zA[g][0][1] = (short)bf16_rne(a0.y * ASCALE);
    zA[g][0][2] = (short)bf16_rne(a0.z * ASCALE); zA[g][0][3] = (short)bf16_rne(a0.w * ASCALE);
    zA[g][0][4] = (short)bf16_rne(a1.x * ASCALE); zA[g][0][5] = (short)bf16_rne(a1.y * ASCALE);
    zA[g][0][6] = (short)bf16_rne(a1.z * ASCALE); zA[g][0][7] = (short)bf16_rne(a1.w * ASCALE);
    zA[g][1][0] = (short)bf16_rne(a2.x * ASCALE); zA[g][1][1] = (short)bf16_rne(a2.y * ASCALE);
    zA[g][1][2] = (short)bf16_rne(a2.z * ASCALE); zA[g][1][3] = (short)bf16_rne(a2.w * ASCALE);
    zA[g][1][4] = (short)bf16_rne(a3.x * ASCALE); zA[g][1][5] = (short)bf16_rne(a3.y * ASCALE);
    zA[g][1][6] = (short)bf16_rne(a3.z * ASCALE); zA[g][1][7] = (short)bf16_rne(a3.w * ASCALE);
  }

  // esq preload (once): 512 thr x float4 = 8 KB
  ((float4*)s_esq)[tid] = ((const float4*)(esqs + nbase))[tid];

  // per-(rowgroup g, acc row r) top-2 packed-key tracking, K0 <= K1 invariant
  unsigned K0[2][4], K1[2][4];
  #pragma unroll
  for (int g = 0; g < 2; ++g)
    #pragma unroll
    for (int r = 0; r < 4; ++r) { K0[g][r] = 0xFFFFFFFFu; K1[g][r] = 0xFFFFFFFFu; }

  // prologue: async-stage chunk 0 into buf0 (2 DMA instructions per wave)
  {
    const ushort_t* g = ehi + (size_t)nbase * 64 + wave * 1024 + lane * 8;
    ushort_t* l = s_buf + wave * 1024 + lane * 8;
    load_lds16(g, l);
    load_lds16(g + 512, l + 512);
  }

  for (int cb = 0; cb < NCH; ++cb) {
    __syncthreads();   // vmcnt(0) waits loads(cb) — issued a compute-phase ago
    if (cb + 1 < NCH) {            // async-stage next chunk into the idle buffer
      int nnext = nbase + (cb + 1) * BN;
      const ushort_t* g = ehi + (size_t)nnext * 64 + wave * 1024 + lane * 8;
      ushort_t* l = s_buf + ((cb + 1) & 1) * 8192 + wave * 1024 + lane * 8;
      load_lds16(g, l);
      load_lds16(g + 512, l + 512);
    }
    const ushort_t* buf = s_buf + (cb & 1) * 8192;
    const float*    esqc = s_esq + cb * BN;

    #pragma unroll
    for (int t = 0; t < BN / 16; ++t) {
      const bf16x8 bh0 = *(const bf16x8*)(buf + t * 1024 + lane * 8);
      const bf16x8 bh1 = *(const bf16x8*)(buf + t * 1024 + 512 + lane * 8);
      float esqv = esqc[t * 16 + c];
      f32x4 cvec = {esqv, esqv, esqv, esqv};       // key bias rides in as C
      unsigned tcv = (((unsigned)(cb * 8 + t)) << 4) | (unsigned)c;  // n_local
      f32x4 acc0 = __builtin_amdgcn_mfma_f32_16x16x32_bf16(zA[0][0], bh0, cvec, 0, 0, 0);
      acc0 = __builtin_amdgcn_mfma_f32_16x16x32_bf16(zA[0][1], bh1, acc0, 0, 0, 0);
      f32x4 acc1 = __builtin_amdgcn_mfma_f32_16x16x32_bf16(zA[1][0], bh0, cvec, 0, 0, 0);
      acc1 = __builtin_amdgcn_mfma_f32_16x16x32_bf16(zA[1][1], bh1, acc1, 0, 0, 0);
      #pragma unroll
      for (int r = 0; r < 4; ++r) {
        unsigned pk = (((unsigned)acc0[r]) << 12) | tcv;   // cvt + lshl_or
        K1[0][r] = umed3(pk, K0[0][r], K1[0][r]);
        K0[0][r] = min(pk, K0[0][r]);
      }
      #pragma unroll
      for (int r = 0; r < 4; ++r) {
        unsigned pk = (((unsigned)acc1[r]) << 12) | tcv;
        K1[1][r] = umed3(pk, K0[1][r], K1[1][r]);
        K0[1][r] = min(pk, K0[1][r]);
      }
    }
  }

  // merge 16 lanes' top-2 -> per-row top-4 keys (row stride 36 words: breaks
  // the all-lanes-same-bank-group pattern of stride 32)
  __syncthreads();
  unsigned* s_k = (unsigned*)smem;             // [256 rows][36 words]
  #pragma unroll
  for (int g = 0; g < 2; ++g)
    #pragma unroll
    for (int r = 0; r < 4; ++r) {
      int rowidx = wave * WROWS + g * 16 + q * 4 + r;  // C layout: row = q*4 + reg
      int base = rowidx * 36 + c * 2;
      s_k[base + 0] = K0[g][r]; s_k[base + 1] = K1[g][r];
    }
  __syncthreads();
  if (tid < BROWS) {
    unsigned M0 = 0xFFFFFFFFu, M1 = 0xFFFFFFFFu, M2 = 0xFFFFFFFFu, M3 = 0xFFFFFFFFu;
    const uint4* sv = (const uint4*)(s_k + tid * 36);
    #pragma unroll
    for (int v4 = 0; v4 < 8; ++v4) {
      uint4 kk = sv[v4];
      unsigned vals[4] = {kk.x, kk.y, kk.z, kk.w};
      #pragma unroll
      for (int u = 0; u < 4; ++u) {
        unsigned v = vals[u];
        M3 = umed3(v, M2, M3);
        M2 = umed3(v, M1, M2);
        M1 = umed3(v, M0, M1);
        M0 = min(v, M0);
      }
    }
    int grow = blockIdx.y * BROWS + tid;
    unsigned* cp = candk + ((size_t)grow * GCHUNKS + blockIdx.x) * 4;
    cp[0] = M0; cp[1] = M1; cp[2] = M2; cp[3] = M3;    // raw keys (qi<<12|n_local)
  }
}

// ------- kernel 3: key-pruned np-fp32-exact rescore, outputs ----------------
// grid = L/32 blocks, block 512 (8 waves); wave: 4 rows, 32 cand-groups x 2
// lanes.  Per-row: one coalesced 128B candk read, 6-step u32 prune reduce,
// pruned fp64 dot (typically 1-2 groups), 5-step 64-bit key reduce.  Loss
// accumulated per-lane from the already-loaded winner values (no fp64 dot
// carry, no np_sum64 — zsq32 is precomputed).
__global__ __launch_bounds__(512, 6) void vq_refine(const float* __restrict__ z,
                                                    const float* __restrict__ e,
                                                    const float* __restrict__ esq32,
                                                    const float* __restrict__ zsq32,
                                                    const unsigned* __restrict__ candk,
                                                    float* __restrict__ out,
                                                    double* __restrict__ partials) {
  const int tid = threadIdx.x;
  const int wave = tid >> 6, lane = tid & 63;
  const int g = lane >> 1, s = lane & 1;      // 32 cand-groups x 2 lanes
  __shared__ double sp[8];
  double wl = 0.0;                             // per-lane loss partial
  for (int it = 0; it < 4; ++it) {
    int row = blockIdx.x * 32 + wave * 4 + it;
    float zf = z[(size_t)row * D_DIM + lane];
    float zsqv = zsq32[row];
    unsigned k = candk[(size_t)row * 32 + g];  // coalesced 128 B per row
    unsigned qi = k >> 12;
    unsigned n  = ((unsigned)(g >> 2)) * (unsigned)NPB + (k & 4095u);
    unsigned gkey = (qi << 14) | n;            // globally ordered (qi, then n)
    unsigned m = gkey;
    #pragma unroll
    for (int o = 1; o < 64; o <<= 1) m = min(m, (unsigned)__shfl_xor((int)m, o));
    unsigned minqi = m >> 14;
    bool part = qi <= minqi + QDELTA;
    unsigned long long key = ~0ull;
    if (part) {                                // both lanes of a pair agree
      const float4* ep = (const float4*)(e + (size_t)n * D_DIM + s * 32);
      const float4* zp = (const float4*)(z + (size_t)row * D_DIM + s * 32);
      double da = 0.0, db = 0.0, dc = 0.0, dd = 0.0;
      #pragma unroll
      for (int h = 0; h < 2; ++h) {
        float4 e0 = ep[h * 4 + 0], e1 = ep[h * 4 + 1];
        float4 e2 = ep[h * 4 + 2], e3 = ep[h * 4 + 3];
        float4 z0 = zp[h * 4 + 0], z1 = zp[h * 4 + 1];
        float4 z2 = zp[h * 4 + 2], z3 = zp[h * 4 + 3];
        da = fma((double)e0.x, (double)z0.x, da); da = fma((double)e0.y, (double)z0.y, da);
        da = fma((double)e0.z, (double)z0.z, da); da = fma((double)e0.w, (double)z0.w, da);
        db = fma((double)e1.x, (double)z1.x, db); db = fma((double)e1.y, (double)z1.y, db);
        db = fma((double)e1.z, (double)z1.z, db); db = fma((double)e1.w, (double)z1.w, db);
        dc = fma((double)e2.x, (double)z2.x, dc); dc = fma((double)e2.y, (double)z2.y, dc);
        dc = fma((double)e2.z, (double)z2.z, dc); dc = fma((double)e2.w, (double)z2.w, dc);
        dd = fma((double)e3.x, (double)z3.x, dd); dd = fma((double)e3.y, (double)z3.y, dd);
        dd = fma((double)e3.z, (double)z3.z, dd); dd = fma((double)e3.w, (double)z3.w, dd);
      }
      double dot = (da + db) + (dc + dd);
      dot += __shfl_xor(dot, 1);               // pair-mate has same `part`
      // emulate np fp32: d = fl32( fl32(zsq + esq) - fl32(2*dot) )
      float t2 = (float)(2.0 * dot);
      float T1 = zsqv + esq32[n];
      float d  = T1 - t2;                      // d ~ 64 > 0: bits are monotone
      key  = ((unsigned long long)__float_as_uint(d) << 14) | n;  // tie: lower n
    }
    #pragma unroll
    for (int o = 2; o <= 32; o <<= 1) {        // pair-mates equal; 5 steps
      unsigned long long ok = __shfl_xor(key, o);
      key = ok < key ? ok : key;
    }
    int win = (int)(key & 16383u);
    // outputs (element layout; whole wave)
    float be = e[(size_t)win * D_DIM + lane];
    out[(size_t)row * D_DIM + lane] = zf + (be - zf);   // fp32 op-order ST
    if (lane == 0) out[(size_t)L_TOK * D_DIM + 1 + row] = (float)win;
    double dd2 = (double)be - (double)zf;
    wl += dd2 * dd2;                           // per-lane loss contribution
  }
  #pragma unroll
  for (int o = 32; o; o >>= 1) wl += __shfl_xor(wl, o);
  if (lane == 0) sp[wave] = wl;
  __syncthreads();
  if (tid == 0) {
    double t = 0.0;
    #pragma unroll
    for (int w = 0; w < 8; ++w) t += sp[w];
    partials[blockIdx.x] = t;
  }
}

// ---------------- kernel 4: finalize loss (1024 partials) --------------------
__global__ __launch_bounds__(512) void vq_loss(const double* __restrict__ partials,
                                               float* __restrict__ out) {
  int tid = threadIdx.x;
  double v = partials[tid] + partials[tid + 512];
  #pragma unroll
  for (int o = 32; o; o >>= 1) v += __shfl_xor(v, o);
  __shared__ double sp[8];
  if ((tid & 63) == 0) sp[tid >> 6] = v;
  __syncthreads();
  if (tid == 0) {
    double tot = 0.0;
    #pragma unroll
    for (int w = 0; w < 8; ++w) tot += sp[w];
    // loss = beta*mean + mean = 1.25 * mean((z_q - z)^2)
    out[(size_t)L_TOK * D_DIM] = (float)(1.25 * tot / (double)((size_t)L_TOK * D_DIM));
  }
}

extern "C" void kernel_launch(void* const* d_in, const int* in_sizes, int n_in,
                              void* d_out, int out_size, void* d_ws, size_t ws_size,
                              hipStream_t stream) {
  const float* z = (const float*)d_in[0];       // (32768, 64) fp32
  const float* e = (const float*)d_in[1];       // (16384, 64) fp32
  float* out = (float*)d_out;                   // [z_q_st | loss | indices-as-f32]
  char* ws = (char*)d_ws;                       // needs ~6.3 MB

  ushort_t* ehi   = (ushort_t*)(ws + WS_EHI);
  float*    esq32 = (float*)(ws + WS_ESQ32);
  float*    esqs  = (float*)(ws + WS_ESQS);
  float*    zsq32 = (float*)(ws + WS_ZSQ32);
  unsigned* candk = (unsigned*)(ws + WS_CAND);
  double*   parts = (double*)(ws + WS_PART);

  vq_prep<<<EBLK + ZBLK, 256, 0, stream>>>(e, z, ehi, esq32, esqs, zsq32);
  vq_argmin<<<dim3(GCHUNKS, L_TOK / BROWS), 512, 0, stream>>>(z, ehi, esqs, candk);
  vq_refine<<<RBLOCKS, 512, 0, stream>>>(z, e, esq32, zsq32, candk, out, parts);
  vq_loss<<<1, 512, 0, stream>>>(parts, out);
}